// Round 1
// baseline (434.890 us; speedup 1.0000x reference)
//
#include <hip/hip_runtime.h>

// ---------------------------------------------------------------------------
// Shapes (fixed): B=2, N=256, NODE_DIM=256, EDGE_DIM=64, H=8, D=32
// d_in: 0 nodes[2,256,256] 1 edges[2,256,256,64] 2 W_qkv[256,768] 3 b_qkv[768]
//       4 W_ss[64,512] 5 b_ss[512] 6 W_nodes[256,256] 7 b_nodes[256]
//       8 W_edges[256,64] 9 b_edges[64]   (all fp32)
// d_out: new_nodes[2,256,256] (131072 f) ++ new_edges_out[2,256,256,64] (8388608 f)
// ws: qkv 393216 f | logits/P 1048576 f | weighted 131072 f  = 6.1 MB
// ---------------------------------------------------------------------------

#define CF4(p) (*reinterpret_cast<const float4*>(p))
#define CF2(p) (*reinterpret_cast<const float2*>(p))
#define F4(p)  (*reinterpret_cast<float4*>(p))
#define F2(p)  (*reinterpret_cast<float2*>(p))

__device__ __forceinline__ float lrelu(float x) { return x > 0.f ? x : 0.1f * x; }

// --- K1/K5: C[M,Nn] = A[M,K] @ B[K,Nn] + bias, 64x64 tile, 256 thr, 4x4 micro
__global__ __launch_bounds__(256) void gemm_bias_kernel(
    const float* __restrict__ A, const float* __restrict__ B,
    const float* __restrict__ bias, float* __restrict__ C,
    int M, int Nn, int K)
{
  __shared__ float As[16][68];   // [k][row]
  __shared__ float Bs[16][68];   // [k][col]
  const int t  = threadIdx.x;
  const int nbx = Nn >> 6;
  const int bx = blockIdx.x % nbx;
  const int by = blockIdx.x / nbx;
  const int r0 = by << 6, c0 = bx << 6;
  const int tx = t & 15, ty = t >> 4;
  float acc[4][4];
#pragma unroll
  for (int i = 0; i < 4; ++i)
#pragma unroll
    for (int j = 0; j < 4; ++j) acc[i][j] = 0.f;

  for (int kt = 0; kt < K; kt += 16) {
    {
      const int r = t >> 2, k4 = (t & 3) << 2;
      const float4 a = CF4(A + (size_t)(r0 + r) * K + kt + k4);
      As[k4 + 0][r] = a.x; As[k4 + 1][r] = a.y; As[k4 + 2][r] = a.z; As[k4 + 3][r] = a.w;
    }
    {
      const int kk = t >> 4, c4 = (t & 15) << 2;
      F4(&Bs[kk][c4]) = CF4(B + (size_t)(kt + kk) * Nn + c0 + c4);
    }
    __syncthreads();
#pragma unroll
    for (int kk = 0; kk < 16; ++kk) {
      const float4 av = F4(&As[kk][ty << 2]);
      const float4 bv = F4(&Bs[kk][tx << 2]);
      const float aa[4] = {av.x, av.y, av.z, av.w};
      const float bb[4] = {bv.x, bv.y, bv.z, bv.w};
#pragma unroll
      for (int rr = 0; rr < 4; ++rr)
#pragma unroll
        for (int cc = 0; cc < 4; ++cc)
          acc[rr][cc] = fmaf(aa[rr], bb[cc], acc[rr][cc]);
    }
    __syncthreads();
  }
  const float4 bv = CF4(bias + c0 + (tx << 2));
  const float bb[4] = {bv.x, bv.y, bv.z, bv.w};
#pragma unroll
  for (int rr = 0; rr < 4; ++rr) {
    float4 o;
    o.x = acc[rr][0] + bb[0]; o.y = acc[rr][1] + bb[1];
    o.z = acc[rr][2] + bb[2]; o.w = acc[rr][3] + bb[3];
    F4(C + (size_t)(r0 + (ty << 2) + rr) * Nn + c0 + (tx << 2)) = o;
  }
}

// --- K2: fused  ss-GEMM -> new_edges -> {logits, lrelu -> @W_edges}
// block = (b, q, k-block of 64 rows). 256 thr: cg=t&31 (col pairs), rg=t>>5 (8 rows).
// chunk loop ch=0..3 over c0=64*ch: GEMM1 (K=64) -> ne regs -> logits shfl-reduce
// -> lrelu to LDS -> GEMM2 partial (K=64).
__global__ __launch_bounds__(256, 4) void edge_main_kernel(
    const float* __restrict__ edges, const float* __restrict__ qkv,
    const float* __restrict__ W_ss, const float* __restrict__ b_ss,
    const float* __restrict__ W_edges, const float* __restrict__ b_edges,
    float* __restrict__ out_edges, float* __restrict__ logits)
{
  __shared__ float eT[64][68];   // [i (edge ch)][r (k-row)]
  __shared__ float neL[64][68];  // [c_local][r]  lrelu(ne) for current chunk

  const int t   = threadIdx.x;
  const int blk = blockIdx.x;          // ((b*256+q)*4 + kb)
  const int kb  = blk & 3;
  const int q   = (blk >> 2) & 255;
  const int b   = blk >> 10;
  const int k0  = kb << 6;

  // stage E tile [64 rows x 64 ch] transposed into LDS
  const float* eBase = edges + ((size_t)((b * 256 + q) * 256 + k0)) * 64;
#pragma unroll
  for (int u = 0; u < 4; ++u) {
    const int f = t + u * 256;          // float4 id 0..1023
    const int r = f >> 4;
    const int i = (f & 15) << 2;
    const float4 v = CF4(eBase + r * 64 + i);
    eT[i + 0][r] = v.x; eT[i + 1][r] = v.y; eT[i + 2][r] = v.z; eT[i + 3][r] = v.w;
  }
  __syncthreads();

  const int cg = t & 31;
  const int rg = t >> 5;
  const int r0 = rg << 3;

  const float* qrow  = qkv + (size_t)(b * 256 + q) * 768;         // q part, ch c
  const float* krow0 = qkv + (size_t)(b * 256 + k0) * 768 + 256;  // k part

  float2 acc2[8];                       // GEMM2 acc: 8 rows x 2 j (j = cg*2+{0,1})
#pragma unroll
  for (int rr = 0; rr < 8; ++rr) { acc2[rr].x = 0.f; acc2[rr].y = 0.f; }

  for (int ch = 0; ch < 4; ++ch) {
    const int c0 = ch << 6;
    const int c  = c0 + (cg << 1);      // this thread's 2 channels: c, c+1

    // GEMM1: shift/scale accumulators (bias pre-loaded)
    float2 ash[8], asc[8];
    const float2 bsh = CF2(b_ss + c);
    const float2 bsc = CF2(b_ss + 256 + c);
#pragma unroll
    for (int rr = 0; rr < 8; ++rr) { ash[rr] = bsh; asc[rr] = bsc; }

#pragma unroll 4
    for (int i = 0; i < 64; ++i) {
      const float4 e0 = F4(&eT[i][r0]);
      const float4 e1 = F4(&eT[i][r0 + 4]);
      const float2 ws = CF2(W_ss + i * 512 + c);
      const float2 wc = CF2(W_ss + i * 512 + 256 + c);
      const float er[8] = {e0.x, e0.y, e0.z, e0.w, e1.x, e1.y, e1.z, e1.w};
#pragma unroll
      for (int rr = 0; rr < 8; ++rr) {
        ash[rr].x = fmaf(er[rr], ws.x, ash[rr].x);
        ash[rr].y = fmaf(er[rr], ws.y, ash[rr].y);
        asc[rr].x = fmaf(er[rr], wc.x, asc[rr].x);
        asc[rr].y = fmaf(er[rr], wc.y, asc[rr].y);
      }
    }

    // ne = attn*(1+scale) + shift ; attn = qv*kv  (channel c = h*32+d)
    const float2 qv = CF2(qrow + c);
    float ne0[8], ne1[8], lg[8];
#pragma unroll
    for (int rr = 0; rr < 8; ++rr) {
      const float2 kv = CF2(krow0 + (size_t)(r0 + rr) * 768 + c);
      const float a0 = qv.x * kv.x;
      const float a1 = qv.y * kv.y;
      ne0[rr] = fmaf(a0, 1.f + asc[rr].x, ash[rr].x);
      ne1[rr] = fmaf(a1, 1.f + asc[rr].y, ash[rr].y);
      lg[rr]  = ne0[rr] + ne1[rr];
    }
    // per-head row sum over 32 channels = reduce across 16 lanes (cg mod 16)
#pragma unroll
    for (int m = 1; m < 16; m <<= 1) {
#pragma unroll
      for (int rr = 0; rr < 8; ++rr) lg[rr] += __shfl_xor(lg[rr], m, 64);
    }
    if ((t & 15) == 0) {
      const int h = (ch << 1) + (cg >> 4);
      float* lp = logits + ((size_t)((b * 8 + h) * 256 + q)) * 256 + k0 + r0;
#pragma unroll
      for (int rr = 0; rr < 8; ++rr) lp[rr] = lg[rr] * 0.17677669529663687f; // /sqrt(32)
    }

    __syncthreads();   // prev chunk's GEMM2 readers done before overwrite
    {
      float4 p;
      p.x = lrelu(ne0[0]); p.y = lrelu(ne0[1]); p.z = lrelu(ne0[2]); p.w = lrelu(ne0[3]);
      F4(&neL[(cg << 1) + 0][r0]) = p;
      p.x = lrelu(ne0[4]); p.y = lrelu(ne0[5]); p.z = lrelu(ne0[6]); p.w = lrelu(ne0[7]);
      F4(&neL[(cg << 1) + 0][r0 + 4]) = p;
      p.x = lrelu(ne1[0]); p.y = lrelu(ne1[1]); p.z = lrelu(ne1[2]); p.w = lrelu(ne1[3]);
      F4(&neL[(cg << 1) + 1][r0]) = p;
      p.x = lrelu(ne1[4]); p.y = lrelu(ne1[5]); p.z = lrelu(ne1[6]); p.w = lrelu(ne1[7]);
      F4(&neL[(cg << 1) + 1][r0 + 4]) = p;
    }
    __syncthreads();

    // GEMM2 partial: out[r][j] += lrelu(ne)[r][c0+cc] * W_edges[c0+cc][j]
#pragma unroll 4
    for (int cc = 0; cc < 64; ++cc) {
      const float4 n0 = F4(&neL[cc][r0]);
      const float4 n1 = F4(&neL[cc][r0 + 4]);
      const float2 w  = CF2(W_edges + (size_t)(c0 + cc) * 64 + (cg << 1));
      const float nr[8] = {n0.x, n0.y, n0.z, n0.w, n1.x, n1.y, n1.z, n1.w};
#pragma unroll
      for (int rr = 0; rr < 8; ++rr) {
        acc2[rr].x = fmaf(nr[rr], w.x, acc2[rr].x);
        acc2[rr].y = fmaf(nr[rr], w.y, acc2[rr].y);
      }
    }
  }

  const float2 be = CF2(b_edges + (cg << 1));
  float* oBase = out_edges + ((size_t)((b * 256 + q) * 256 + k0 + r0)) * 64 + (cg << 1);
#pragma unroll
  for (int rr = 0; rr < 8; ++rr) {
    float2 o; o.x = acc2[rr].x + be.x; o.y = acc2[rr].y + be.y;
    F2(oBase + (size_t)rr * 64) = o;
  }
}

// --- K3: softmax over the QUERY axis (faithful to reference), in-place -> P
// one block per (b,h); thread k owns column k; reads coalesced across lanes.
__global__ __launch_bounds__(256) void softmax_q_kernel(float* __restrict__ logits)
{
  const int bh = blockIdx.x;
  const int k  = threadIdx.x;
  float* base = logits + (size_t)bh * 65536;   // [q][k]
  float m = -1e30f;
#pragma unroll 4
  for (int q = 0; q < 256; ++q) m = fmaxf(m, base[q * 256 + k]);
  float s = 0.f;
#pragma unroll 4
  for (int q = 0; q < 256; ++q) s += expf(base[q * 256 + k] - m);
  const float r = 1.f / s;
#pragma unroll 4
  for (int q = 0; q < 256; ++q) base[q * 256 + k] = expf(base[q * 256 + k] - m) * r;
}

// --- K4: weighted[b,q,h*32+d] = sum_k P[b,h,q,k] * v[b,h,k,d]
// grid = b(2)*h(8)*qchunk(4); thread: dg=t&7 (4 d), qg=t>>3 (2 q rows)
__global__ __launch_bounds__(256) void weighted_kernel(
    const float* __restrict__ P, const float* __restrict__ qkv,
    float* __restrict__ weighted)
{
  const int blk = blockIdx.x;
  const int qc = blk & 3, h = (blk >> 2) & 7, b = blk >> 5;
  const int t = threadIdx.x;
  const int dg = t & 7, qg = t >> 3;
  const int q0 = (qc << 6) + (qg << 1);
  const float* Pb = P + (size_t)((b * 8 + h) * 256) * 256;
  const float* vb = qkv + (size_t)b * 256 * 768 + 512 + h * 32 + (dg << 2);
  float a0[4] = {0.f, 0.f, 0.f, 0.f}, a1[4] = {0.f, 0.f, 0.f, 0.f};
#pragma unroll 4
  for (int k = 0; k < 256; ++k) {
    const float4 v = CF4(vb + (size_t)k * 768);
    const float p0 = Pb[(size_t)q0 * 256 + k];
    const float p1 = Pb[(size_t)(q0 + 1) * 256 + k];
    a0[0] = fmaf(p0, v.x, a0[0]); a0[1] = fmaf(p0, v.y, a0[1]);
    a0[2] = fmaf(p0, v.z, a0[2]); a0[3] = fmaf(p0, v.w, a0[3]);
    a1[0] = fmaf(p1, v.x, a1[0]); a1[1] = fmaf(p1, v.y, a1[1]);
    a1[2] = fmaf(p1, v.z, a1[2]); a1[3] = fmaf(p1, v.w, a1[3]);
  }
  float* w = weighted + (size_t)(b * 256 + q0) * 256 + h * 32 + (dg << 2);
  float4 o0, o1;
  o0.x = a0[0]; o0.y = a0[1]; o0.z = a0[2]; o0.w = a0[3];
  o1.x = a1[0]; o1.y = a1[1]; o1.z = a1[2]; o1.w = a1[3];
  F4(w) = o0; F4(w + 256) = o1;
}

extern "C" void kernel_launch(void* const* d_in, const int* in_sizes, int n_in,
                              void* d_out, int out_size, void* d_ws, size_t ws_size,
                              hipStream_t stream) {
  const float* nodes   = (const float*)d_in[0];
  const float* edges   = (const float*)d_in[1];
  const float* W_qkv   = (const float*)d_in[2];
  const float* b_qkv   = (const float*)d_in[3];
  const float* W_ss    = (const float*)d_in[4];
  const float* b_ss    = (const float*)d_in[5];
  const float* W_nodes = (const float*)d_in[6];
  const float* b_nodes = (const float*)d_in[7];
  const float* W_edges = (const float*)d_in[8];
  const float* b_edges = (const float*)d_in[9];

  float* out_nodes = (float*)d_out;            // 131072 floats
  float* out_edges = out_nodes + 131072;       // 8388608 floats

  float* ws       = (float*)d_ws;              // needs 6.1 MB
  float* qkv      = ws;                        // [2,256,768]
  float* logits   = ws + 393216;               // [2,8,256,256] -> becomes P in-place
  float* weighted = ws + 393216 + 1048576;     // [2,256,256]

  // K1: qkv = nodes @ W_qkv + b_qkv    [512,256]@[256,768]
  gemm_bias_kernel<<<96, 256, 0, stream>>>(nodes, W_qkv, b_qkv, qkv, 512, 768, 256);
  // K2: fused edge pipeline (ss GEMM, new_edges, logits, lrelu @ W_edges)
  edge_main_kernel<<<2048, 256, 0, stream>>>(edges, qkv, W_ss, b_ss,
                                             W_edges, b_edges, out_edges, logits);
  // K3: softmax over q axis, in-place logits -> P
  softmax_q_kernel<<<16, 256, 0, stream>>>(logits);
  // K4: weighted = P . V
  weighted_kernel<<<64, 256, 0, stream>>>(logits, qkv, weighted);
  // K5: new_nodes = weighted @ W_nodes + b_nodes   [512,256]@[256,256]
  gemm_bias_kernel<<<32, 256, 0, stream>>>(weighted, W_nodes, b_nodes, out_nodes, 512, 256, 256);
}

// Round 2
// 263.468 us; speedup vs baseline: 1.6506x; 1.6506x over previous
//
#include <hip/hip_runtime.h>

// ---------------------------------------------------------------------------
// Shapes (fixed): B=2, N=256, NODE_DIM=256, EDGE_DIM=64, H=8, D=32
// Strategy: MFMA (bf16 3-term split: AhBh + AhBl + AlBh, ~2^-17 rel err) for
// the two big GEMMs, fused with ne/logits/lrelu in the MFMA C-layout.
// ---------------------------------------------------------------------------

typedef unsigned short ushortT;
typedef short s16x8 __attribute__((ext_vector_type(8)));
typedef float f32x4 __attribute__((ext_vector_type(4)));

#define MFMA16(a, b, c) __builtin_amdgcn_mfma_f32_16x16x32_bf16(a, b, c, 0, 0, 0)

#define CF4(p) (*reinterpret_cast<const float4*>(p))
#define F4(p)  (*reinterpret_cast<float4*>(p))

__device__ __forceinline__ ushortT f2bf(float x) {
  union { float f; unsigned u; } v; v.f = x;
  unsigned r = (v.u + 0x7FFFu + ((v.u >> 16) & 1u)) >> 16;   // RNE
  return (ushortT)r;
}
__device__ __forceinline__ float bf2f(ushortT h) {
  union { unsigned u; float f; } v; v.u = ((unsigned)h) << 16;
  return v.f;
}

// --- prep: transpose + bf16-split weights.  WssT[c][i] (512x64), WeT[j][c] (64x256)
__global__ __launch_bounds__(256) void prep_weights(
    const float* __restrict__ W_ss, const float* __restrict__ W_edges,
    ushortT* __restrict__ WssT_h, ushortT* __restrict__ WssT_l,
    ushortT* __restrict__ WeT_h,  ushortT* __restrict__ WeT_l)
{
  const int idx = blockIdx.x * 256 + threadIdx.x;   // 16384 threads
  for (int e = idx; e < 512 * 64; e += 16384) {
    const int c = e >> 6, i = e & 63;
    const float x = W_ss[i * 512 + c];
    const ushortT h = f2bf(x);
    WssT_h[e] = h;
    WssT_l[e] = f2bf(x - bf2f(h));
  }
  for (int e = idx; e < 64 * 256; e += 16384) {
    const int j = e >> 8, c = e & 255;
    const float x = W_edges[c * 64 + j];
    const ushortT h = f2bf(x);
    WeT_h[e] = h;
    WeT_l[e] = f2bf(x - bf2f(h));
  }
}

// --- K1/K5: C[M,Nn] = A[M,K] @ B[K,Nn] + bias (fp32 VALU; small GEMMs)
__global__ __launch_bounds__(256) void gemm_bias_kernel(
    const float* __restrict__ A, const float* __restrict__ B,
    const float* __restrict__ bias, float* __restrict__ C,
    int M, int Nn, int K)
{
  __shared__ float As[16][68];
  __shared__ float Bs[16][68];
  const int t  = threadIdx.x;
  const int nbx = Nn >> 6;
  const int bx = blockIdx.x % nbx;
  const int by = blockIdx.x / nbx;
  const int r0 = by << 6, c0 = bx << 6;
  const int tx = t & 15, ty = t >> 4;
  float acc[4][4];
#pragma unroll
  for (int i = 0; i < 4; ++i)
#pragma unroll
    for (int j = 0; j < 4; ++j) acc[i][j] = 0.f;

  for (int kt = 0; kt < K; kt += 16) {
    {
      const int r = t >> 2, k4 = (t & 3) << 2;
      const float4 a = CF4(A + (size_t)(r0 + r) * K + kt + k4);
      As[k4 + 0][r] = a.x; As[k4 + 1][r] = a.y; As[k4 + 2][r] = a.z; As[k4 + 3][r] = a.w;
    }
    {
      const int kk = t >> 4, c4 = (t & 15) << 2;
      F4(&Bs[kk][c4]) = CF4(B + (size_t)(kt + kk) * Nn + c0 + c4);
    }
    __syncthreads();
#pragma unroll
    for (int kk = 0; kk < 16; ++kk) {
      const float4 av = F4(&As[kk][ty << 2]);
      const float4 bv = F4(&Bs[kk][tx << 2]);
      const float aa[4] = {av.x, av.y, av.z, av.w};
      const float bb[4] = {bv.x, bv.y, bv.z, bv.w};
#pragma unroll
      for (int rr = 0; rr < 4; ++rr)
#pragma unroll
        for (int cc = 0; cc < 4; ++cc)
          acc[rr][cc] = fmaf(aa[rr], bb[cc], acc[rr][cc]);
    }
    __syncthreads();
  }
  const float4 bv = CF4(bias + c0 + (tx << 2));
  const float bb[4] = {bv.x, bv.y, bv.z, bv.w};
#pragma unroll
  for (int rr = 0; rr < 4; ++rr) {
    float4 o;
    o.x = acc[rr][0] + bb[0]; o.y = acc[rr][1] + bb[1];
    o.z = acc[rr][2] + bb[2]; o.w = acc[rr][3] + bb[3];
    F4(C + (size_t)(r0 + (ty << 2) + rr) * Nn + c0 + (tx << 2)) = o;
  }
}

// --- K2: MFMA edge pipeline.
// Block = (b, q, kh): 128 k-rows. 4 waves x 32 rows. Per chunk ch (64 channels):
//   GEMM1 (ss shift+scale, K=64, 3-term) -> ne in C-layout -> logits (shfl reduce)
//   -> lrelu -> bf16 split -> LDS (swizzled) -> GEMM2 partial (K=64, 3-term).
__global__ __launch_bounds__(256, 2) void edge_mfma_kernel(
    const float* __restrict__ edges, const float* __restrict__ qkv,
    const ushortT* __restrict__ WssT_h, const ushortT* __restrict__ WssT_l,
    const float* __restrict__ b_ss,
    const ushortT* __restrict__ WeT_h, const ushortT* __restrict__ WeT_l,
    const float* __restrict__ b_edges,
    float* __restrict__ out_edges, float* __restrict__ logits)
{
  __shared__ ushortT Eh[128 * 64];
  __shared__ ushortT El[128 * 64];
  __shared__ ushortT Nh[128 * 64];
  __shared__ ushortT Nl[128 * 64];
  __shared__ float qv_l[256];

  const int t    = threadIdx.x;
  const int lane = t & 63;
  const int w    = t >> 6;          // wave 0..3
  const int l15  = lane & 15;
  const int lg   = lane >> 4;       // 0..3
  const int bid  = blockIdx.x;
  const int kh   = bid & 1;
  const int q    = (bid >> 1) & 255;
  const int b    = bid >> 9;
  const int k0   = kh << 7;         // 0 or 128
  const int rw   = w << 5;          // wave row base within 128

  // stage q-row (fp32)
  qv_l[t] = qkv[(size_t)(b * 256 + q) * 768 + t];

  // stage E tile: 128 rows x 64 ch, bf16 hi/lo, XOR-swizzled rows
  const float* eBase = edges + ((size_t)((b * 256 + q) * 256 + k0)) * 64;
#pragma unroll
  for (int u = 0; u < 8; ++u) {
    const int f = t + u * 256;            // float4 id 0..2047
    const int r = f >> 4, i4 = (f & 15) << 2;
    const float4 v = CF4(eBase + r * 64 + i4);
    const ushortT h0 = f2bf(v.x), h1 = f2bf(v.y), h2 = f2bf(v.z), h3 = f2bf(v.w);
    const ushortT e0 = f2bf(v.x - bf2f(h0)), e1 = f2bf(v.y - bf2f(h1)),
                  e2 = f2bf(v.z - bf2f(h2)), e3 = f2bf(v.w - bf2f(h3));
    int byte = r * 128 + i4 * 2; byte ^= (r & 7) << 4;
    *reinterpret_cast<ushort4*>(reinterpret_cast<char*>(Eh) + byte) = make_ushort4(h0, h1, h2, h3);
    *reinterpret_cast<ushort4*>(reinterpret_cast<char*>(El) + byte) = make_ushort4(e0, e1, e2, e3);
  }
  __syncthreads();

  const f32x4 zero4 = {0.f, 0.f, 0.f, 0.f};
  f32x4 accO[2][4];
#pragma unroll
  for (int rt = 0; rt < 2; ++rt)
#pragma unroll
    for (int jt = 0; jt < 4; ++jt) accO[rt][jt] = zero4;

  for (int ch = 0; ch < 4; ++ch) {
    const int c0 = ch << 6;

    // GEMM1 accumulators, bias-initialized (bias depends on col only)
    f32x4 accS[2][4], accC[2][4];
#pragma unroll
    for (int ct = 0; ct < 4; ++ct) {
      const float bs = b_ss[c0 + ct * 16 + l15];
      const float bc = b_ss[256 + c0 + ct * 16 + l15];
      f32x4 vs = {bs, bs, bs, bs}, vc = {bc, bc, bc, bc};
      accS[0][ct] = vs; accS[1][ct] = vs;
      accC[0][ct] = vc; accC[1][ct] = vc;
    }

    // ---- GEMM1: K=64 (2 k-steps of 32), 3-term split
#pragma unroll
    for (int ks = 0; ks < 2; ++ks) {
      s16x8 bsh[4], bsl[4], bch[4], bcl[4];
#pragma unroll
      for (int ct = 0; ct < 4; ++ct) {
        const size_t off = (size_t)(c0 + ct * 16 + l15) * 64 + 32 * ks + 8 * lg;
        bsh[ct] = *reinterpret_cast<const s16x8*>(WssT_h + off);
        bsl[ct] = *reinterpret_cast<const s16x8*>(WssT_l + off);
        bch[ct] = *reinterpret_cast<const s16x8*>(WssT_h + off + 256 * 64);
        bcl[ct] = *reinterpret_cast<const s16x8*>(WssT_l + off + 256 * 64);
      }
#pragma unroll
      for (int rt = 0; rt < 2; ++rt) {
        const int row = rw + rt * 16 + l15;
        int byte = row * 128 + (32 * ks + 8 * lg) * 2; byte ^= (row & 7) << 4;
        const s16x8 ah = *reinterpret_cast<const s16x8*>(reinterpret_cast<const char*>(Eh) + byte);
        const s16x8 al = *reinterpret_cast<const s16x8*>(reinterpret_cast<const char*>(El) + byte);
#pragma unroll
        for (int ct = 0; ct < 4; ++ct) {
          accS[rt][ct] = MFMA16(ah, bsh[ct], accS[rt][ct]);
          accS[rt][ct] = MFMA16(ah, bsl[ct], accS[rt][ct]);
          accS[rt][ct] = MFMA16(al, bsh[ct], accS[rt][ct]);
          accC[rt][ct] = MFMA16(ah, bch[ct], accC[rt][ct]);
          accC[rt][ct] = MFMA16(ah, bcl[ct], accC[rt][ct]);
          accC[rt][ct] = MFMA16(al, bch[ct], accC[rt][ct]);
        }
      }
    }

    // ---- elementwise: ne = attn*(1+scale)+shift; logits partials; lrelu->LDS
    float lgacc[2][2][4];
#pragma unroll
    for (int rt = 0; rt < 2; ++rt)
#pragma unroll
      for (int hh = 0; hh < 2; ++hh)
#pragma unroll
        for (int r = 0; r < 4; ++r) lgacc[rt][hh][r] = 0.f;

#pragma unroll
    for (int rt = 0; rt < 2; ++rt) {
#pragma unroll
      for (int ct = 0; ct < 4; ++ct) {
        const float qvc = qv_l[c0 + ct * 16 + l15];
        const float* kvp = qkv + (size_t)(b * 256 + k0 + rw + rt * 16 + lg * 4) * 768
                               + 256 + c0 + ct * 16 + l15;
#pragma unroll
        for (int r = 0; r < 4; ++r) {
          const float kvv = kvp[(size_t)r * 768];
          const float a  = qvc * kvv;
          const float ne = fmaf(a, accC[rt][ct][r], a) + accS[rt][ct][r];
          lgacc[rt][ct >> 1][r] += ne;
          const float nel = ne > 0.f ? ne : 0.1f * ne;
          const ushortT nh = f2bf(nel);
          const ushortT nl = f2bf(nel - bf2f(nh));
          const int row = rw + rt * 16 + lg * 4 + r;
          int byte = row * 128 + (ct * 16 + l15) * 2; byte ^= (row & 7) << 4;
          *reinterpret_cast<ushortT*>(reinterpret_cast<char*>(Nh) + byte) = nh;
          *reinterpret_cast<ushortT*>(reinterpret_cast<char*>(Nl) + byte) = nl;
        }
      }
    }

    // logits: reduce over 16 lanes (cols) and write (heads 2ch, 2ch+1)
#pragma unroll
    for (int rt = 0; rt < 2; ++rt)
#pragma unroll
      for (int hh = 0; hh < 2; ++hh)
#pragma unroll
        for (int r = 0; r < 4; ++r) {
          float v = lgacc[rt][hh][r];
          v += __shfl_xor(v, 1);
          v += __shfl_xor(v, 2);
          v += __shfl_xor(v, 4);
          v += __shfl_xor(v, 8);
          lgacc[rt][hh][r] = v;
        }
    if (l15 == 0) {
#pragma unroll
      for (int rt = 0; rt < 2; ++rt)
#pragma unroll
        for (int hh = 0; hh < 2; ++hh) {
          float4 o;
          o.x = lgacc[rt][hh][0] * 0.17677669529663687f;
          o.y = lgacc[rt][hh][1] * 0.17677669529663687f;
          o.z = lgacc[rt][hh][2] * 0.17677669529663687f;
          o.w = lgacc[rt][hh][3] * 0.17677669529663687f;
          const int h = ch * 2 + hh;
          const int krow = k0 + rw + rt * 16 + lg * 4;
          F4(logits + ((size_t)((b * 8 + h) * 256 + q)) * 256 + krow) = o;
        }
    }

    // ---- GEMM2 partial: K=64 of this chunk, 3-term split (row-private LDS, no barrier)
#pragma unroll
    for (int ks = 0; ks < 2; ++ks) {
      s16x8 wh[4], wl[4];
#pragma unroll
      for (int jt = 0; jt < 4; ++jt) {
        const size_t off = (size_t)(jt * 16 + l15) * 256 + c0 + 32 * ks + 8 * lg;
        wh[jt] = *reinterpret_cast<const s16x8*>(WeT_h + off);
        wl[jt] = *reinterpret_cast<const s16x8*>(WeT_l + off);
      }
#pragma unroll
      for (int rt = 0; rt < 2; ++rt) {
        const int row = rw + rt * 16 + l15;
        int byte = row * 128 + (32 * ks + 8 * lg) * 2; byte ^= (row & 7) << 4;
        const s16x8 anh = *reinterpret_cast<const s16x8*>(reinterpret_cast<const char*>(Nh) + byte);
        const s16x8 anl = *reinterpret_cast<const s16x8*>(reinterpret_cast<const char*>(Nl) + byte);
#pragma unroll
        for (int jt = 0; jt < 4; ++jt) {
          accO[rt][jt] = MFMA16(anh, wh[jt], accO[rt][jt]);
          accO[rt][jt] = MFMA16(anh, wl[jt], accO[rt][jt]);
          accO[rt][jt] = MFMA16(anl, wh[jt], accO[rt][jt]);
        }
      }
    }
  }

  // epilogue: out_edges[(b,q,k)][j] = accO + b_edges[j]
#pragma unroll
  for (int rt = 0; rt < 2; ++rt)
#pragma unroll
    for (int jt = 0; jt < 4; ++jt) {
      const float be = b_edges[jt * 16 + l15];
#pragma unroll
      for (int r = 0; r < 4; ++r) {
        const int krow = k0 + rw + rt * 16 + lg * 4 + r;
        out_edges[((size_t)((b * 256 + q) * 256 + krow)) * 64 + jt * 16 + l15] =
            accO[rt][jt][r] + be;
      }
    }
}

// --- K3: per-(b,h,k) softmax-over-q stats: m = max_q, r = 1/sum_q exp(x-m)
__global__ __launch_bounds__(256) void softmax_stats_kernel(
    const float* __restrict__ logits, float* __restrict__ mOut, float* __restrict__ rOut)
{
  __shared__ float sm[8][33], sx[8][33];
  const int bh = blockIdx.x >> 3, kc = blockIdx.x & 7;
  const int kl = threadIdx.x & 31, qg = threadIdx.x >> 5;
  const float* base = logits + (size_t)bh * 65536 + kc * 32 + kl;
  float arr[32];
#pragma unroll
  for (int i = 0; i < 32; ++i) arr[i] = base[(size_t)(qg * 32 + i) * 256];
  float m = arr[0];
#pragma unroll
  for (int i = 1; i < 32; ++i) m = fmaxf(m, arr[i]);
  float s = 0.f;
#pragma unroll
  for (int i = 0; i < 32; ++i) s += __expf(arr[i] - m);
  sm[qg][kl] = m; sx[qg][kl] = s;
  __syncthreads();
  if (threadIdx.x < 32) {
    float M = sm[0][kl];
#pragma unroll
    for (int g = 1; g < 8; ++g) M = fmaxf(M, sm[g][kl]);
    float S = 0.f;
#pragma unroll
    for (int g = 0; g < 8; ++g) S += sx[g][kl] * __expf(sm[g][kl] - M);
    mOut[bh * 256 + kc * 32 + kl] = M;
    rOut[bh * 256 + kc * 32 + kl] = 1.f / S;
  }
}

// --- K4: weighted[b,q,h*32+d] = sum_k exp(l-m_k)*r_k * v[k,h*32+d]  (fused P)
__global__ __launch_bounds__(256) void weighted_fused_kernel(
    const float* __restrict__ logits, const float* __restrict__ mOut,
    const float* __restrict__ rOut, const float* __restrict__ qkv,
    float* __restrict__ weighted)
{
  __shared__ float P[32][260];
  __shared__ float mc[256], rc[256];
  const int qt = blockIdx.x & 7, h = (blockIdx.x >> 3) & 7, b = blockIdx.x >> 6;
  const int bh = b * 8 + h;
  const int t = threadIdx.x;
  mc[t] = mOut[bh * 256 + t];
  rc[t] = rOut[bh * 256 + t];
  __syncthreads();
  const float* lb = logits + (size_t)bh * 65536 + (size_t)qt * 32 * 256;
#pragma unroll
  for (int u = 0; u < 8; ++u) {
    const int f = t + u * 256;          // float4 id 0..2047
    const int qq = f >> 6, k4 = (f & 63) << 2;
    const float4 v = CF4(lb + qq * 256 + k4);
    P[qq][k4 + 0] = __expf(v.x - mc[k4 + 0]) * rc[k4 + 0];
    P[qq][k4 + 1] = __expf(v.y - mc[k4 + 1]) * rc[k4 + 1];
    P[qq][k4 + 2] = __expf(v.z - mc[k4 + 2]) * rc[k4 + 2];
    P[qq][k4 + 3] = __expf(v.w - mc[k4 + 3]) * rc[k4 + 3];
  }
  __syncthreads();
  const int dg = t & 7, qq = t >> 3;
  const float* vb = qkv + (size_t)b * 196608 + 512 + h * 32 + dg * 4;
  float a0 = 0.f, a1 = 0.f, a2 = 0.f, a3 = 0.f;
#pragma unroll 4
  for (int k = 0; k < 256; ++k) {
    const float p = P[qq][k];
    const float4 v = CF4(vb + (size_t)k * 768);
    a0 = fmaf(p, v.x, a0); a1 = fmaf(p, v.y, a1);
    a2 = fmaf(p, v.z, a2); a3 = fmaf(p, v.w, a3);
  }
  float4 o; o.x = a0; o.y = a1; o.z = a2; o.w = a3;
  F4(weighted + ((size_t)(b * 256 + qt * 32 + qq)) * 256 + h * 32 + dg * 4) = o;
}

extern "C" void kernel_launch(void* const* d_in, const int* in_sizes, int n_in,
                              void* d_out, int out_size, void* d_ws, size_t ws_size,
                              hipStream_t stream) {
  const float* nodes   = (const float*)d_in[0];
  const float* edges   = (const float*)d_in[1];
  const float* W_qkv   = (const float*)d_in[2];
  const float* b_qkv   = (const float*)d_in[3];
  const float* W_ss    = (const float*)d_in[4];
  const float* b_ss    = (const float*)d_in[5];
  const float* W_nodes = (const float*)d_in[6];
  const float* b_nodes = (const float*)d_in[7];
  const float* W_edges = (const float*)d_in[8];
  const float* b_edges = (const float*)d_in[9];

  float* out_nodes = (float*)d_out;            // 131072 floats
  float* out_edges = out_nodes + 131072;       // 8388608 floats

  float* wsf      = (float*)d_ws;
  float* qkv      = wsf;                       // [2,256,768]
  float* logits   = wsf + 393216;              // [2,8,256,256]
  float* weighted = wsf + 1441792;             // [2,256,256]
  float* mcol     = wsf + 1572864;             // [16,256]
  float* rcol     = wsf + 1576960;             // [16,256]
  ushortT* wss    = (ushortT*)(wsf + 1581056); // bf16 region
  ushortT* WssT_h = wss;                       // 512*64
  ushortT* WssT_l = wss + 32768;
  ushortT* WeT_h  = wss + 65536;               // 64*256
  ushortT* WeT_l  = wss + 81920;               // end: 98304 ushorts (~6.52 MB total)

  prep_weights<<<64, 256, 0, stream>>>(W_ss, W_edges, WssT_h, WssT_l, WeT_h, WeT_l);
  gemm_bias_kernel<<<96, 256, 0, stream>>>(nodes, W_qkv, b_qkv, qkv, 512, 768, 256);
  edge_mfma_kernel<<<1024, 256, 0, stream>>>(edges, qkv, WssT_h, WssT_l, b_ss,
                                             WeT_h, WeT_l, b_edges, out_edges, logits);
  softmax_stats_kernel<<<128, 256, 0, stream>>>(logits, mcol, rcol);
  weighted_fused_kernel<<<128, 256, 0, stream>>>(logits, mcol, rcol, qkv, weighted);
  gemm_bias_kernel<<<32, 256, 0, stream>>>(weighted, W_nodes, b_nodes, out_nodes, 512, 256, 256);
}